// Round 1
// baseline (23277.504 us; speedup 1.0000x reference)
//
#include <hip/hip_runtime.h>
#include <math.h>

// Neural Hawkes Process scan: B=256 batch, T=512 steps, H=512 hidden, E=32 events.
// Persistent-kernel design: 256 blocks (1/CU), block (bt,ct) owns rows [64bt,64bt+64)
// x hcols [8ct, 8ct+8). Grid barrier per timestep via per-block epoch flags.
// h history == hidden_states output (each t-slice written once -> race-free).
// gx trick: x-contribution of gate GEMM precomputed once over the 32 embeddings.

#define Bb   256
#define Tt   512
#define Hh   512
#define Ee   32
#define G5H  2560
#define NBLK 256
#define NTHR 256

__device__ __forceinline__ float softplusf(float x) {
    return fmaxf(x, 0.f) + log1pf(expf(-fabsf(x)));
}

__device__ __forceinline__ void lam_eval(int b, int t, int e,
                                         const float* __restrict__ out_hid,
                                         const float* __restrict__ Wi,
                                         const float* __restrict__ bi,
                                         float* __restrict__ out_int) {
    const float* hp = out_hid + ((size_t)b * Tt + t) * Hh;
    float a0 = 0.f, a1 = 0.f, a2 = 0.f, a3 = 0.f;
    for (int k = 0; k < Hh; k += 4) {
        const float4 hv = *(const float4*)(hp + k);
        a0 += hv.x * Wi[(k    ) * Ee + e];
        a1 += hv.y * Wi[(k + 1) * Ee + e];
        a2 += hv.z * Wi[(k + 2) * Ee + e];
        a3 += hv.w * Wi[(k + 3) * Ee + e];
    }
    const float s = (a0 + a1) + (a2 + a3) + bi[e];
    out_int[((size_t)b * Tt + t) * Ee + e] = softplusf(s);
}

__global__ __launch_bounds__(NTHR, 1)
void nhp_main(const int* __restrict__ events, const float* __restrict__ times,
              const float* __restrict__ emb, const float* __restrict__ Wg,
              const float* __restrict__ bg, const float* __restrict__ Wi,
              const float* __restrict__ bi, float* __restrict__ out_int,
              float* __restrict__ out_hid, unsigned* __restrict__ flags) {
    __shared__ float h_lds[64][132];   // 64 rows x 128 k chunk (+4 pad)
    __shared__ float w_lds[40][132];   // 40 gate-cols x 128 k chunk, k-contiguous
    __shared__ float gx[32][40];       // precomputed emb@Wx + b per event type
    __shared__ int   ev_s[64];
    __shared__ float dt_s[64];

    const int tid  = threadIdx.x;
    const int bid  = blockIdx.x;
    const int xcd  = bid & 7;          // XCD-aware: same-XCD blocks share W cols
    const int l    = bid >> 3;
    const int ct   = xcd * 8 + (l & 7);   // 0..63 column tile
    const int bt   = l >> 3;              // 0..3  batch tile
    const int r0   = bt * 64;
    const int j    = tid & 7;             // local hcol within tile
    const int rowg = tid >> 3;            // 0..31; thread owns rows rowg, rowg+32
    const int hcol = ct * 8 + j;

    // ---- one-time: gx[e][lc] = emb[e] @ Wx[:, gcol] + b_gates[gcol]
    for (int u = tid; u < 32 * 40; u += NTHR) {
        const int e  = u / 40, lc = u - e * 40;
        const int g  = lc >> 3, jj = lc & 7;
        const int gcol = g * Hh + ct * 8 + jj;
        float acc = bg[gcol];
        const float* er = emb + (size_t)e * Hh;
        for (int k = 0; k < Hh; k += 4) {
            acc += er[k    ] * Wg[(size_t)(k    ) * G5H + gcol];
            acc += er[k + 1] * Wg[(size_t)(k + 1) * G5H + gcol];
            acc += er[k + 2] * Wg[(size_t)(k + 2) * G5H + gcol];
            acc += er[k + 3] * Wg[(size_t)(k + 3) * G5H + gcol];
        }
        gx[e][lc] = acc;
    }
    float c0 = 0.f, c1 = 0.f;
    __syncthreads();

    unsigned epoch = 0;
    for (int p = 0; p < Tt; ++p) {
        // stage events / dt for this block's 64 rows
        if (tid < 64) {
            const int b = r0 + tid;
            ev_s[tid] = events[b * Tt + p];
            const float tp = times[b * Tt + p];
            if (p == 0) dt_s[tid] = tp;
            else        dt_s[tid] = tp - times[b * Tt + p - 1];
        }
        __syncthreads();

        float acc0[5], acc1[5];
        {
            const int e0 = ev_s[rowg], e1 = ev_s[rowg + 32];
            #pragma unroll
            for (int g = 0; g < 5; ++g) {
                acc0[g] = gx[e0][g * 8 + j];
                acc1[g] = gx[e1][g * 8 + j];
            }
        }

        if (p > 0) {  // h_0 = 0 -> skip GEMM at p==0
            for (int kc = 0; kc < Hh; kc += 128) {
                // stage h chunk from hidden_states[:, p-1, :]
                #pragma unroll
                for (int i = 0; i < 8; ++i) {
                    const int f = tid + i * NTHR;
                    const int row = f >> 5, kq = f & 31;
                    const size_t gidx = ((size_t)(r0 + row) * Tt + (p - 1)) * Hh + kc + kq * 4;
                    *(float4*)&h_lds[row][kq * 4] = *(const float4*)(out_hid + gidx);
                }
                // stage Wh chunk transposed (k-contiguous per gate-col)
                #pragma unroll
                for (int i = 0; i < 5; ++i) {
                    const int u  = tid + i * NTHR;       // 0..1279
                    const int lc = u % 40, kq = u / 40;  // kq 0..31
                    const int g  = lc >> 3, jj = lc & 7;
                    const int gcol = g * Hh + ct * 8 + jj;
                    const int krow = Hh + kc + kq * 4;
                    float4 wv;
                    wv.x = Wg[(size_t)(krow    ) * G5H + gcol];
                    wv.y = Wg[(size_t)(krow + 1) * G5H + gcol];
                    wv.z = Wg[(size_t)(krow + 2) * G5H + gcol];
                    wv.w = Wg[(size_t)(krow + 3) * G5H + gcol];
                    *(float4*)&w_lds[lc][kq * 4] = wv;
                }
                __syncthreads();
                #pragma unroll 2
                for (int kq = 0; kq < 32; ++kq) {
                    const float4 a0 = *(const float4*)&h_lds[rowg     ][kq * 4];
                    const float4 a1 = *(const float4*)&h_lds[rowg + 32][kq * 4];
                    #pragma unroll
                    for (int g = 0; g < 5; ++g) {
                        const float4 w = *(const float4*)&w_lds[g * 8 + j][kq * 4];
                        acc0[g] += a0.x * w.x + a0.y * w.y + a0.z * w.z + a0.w * w.w;
                        acc1[g] += a1.x * w.x + a1.y * w.y + a1.z * w.z + a1.w * w.w;
                    }
                }
                __syncthreads();
            }
        }

        // gate math + state update; write h_n into hidden_states[:, p, :]
        #pragma unroll
        for (int r = 0; r < 2; ++r) {
            const float* ac = r ? acc1 : acc0;
            const int lrow = rowg + r * 32;
            const float ig  = tanhf(ac[0]);
            const float fg  = tanhf(ac[1]);
            const float og  = tanhf(ac[2]);
            const float ctl = tanhf(ac[3]);
            const float dec = softplusf(ac[4]);
            const float cprev = r ? c1 : c0;
            const float cdec  = cprev * expf(-dec * dt_s[lrow]);
            const float cn    = fg * cdec + ig * ctl;
            if (r) c1 = cn; else c0 = cn;
            const float hn = og * tanhf(cn);
            const int b = r0 + lrow;
            out_hid[((size_t)b * Tt + p) * Hh + hcol] = hn;
        }

        // ---- barrier arrive (release my h_n writes)
        __syncthreads();                       // drains vmem (compiler emits vmcnt(0))
        ++epoch;
        if (tid == 0) {
            __builtin_amdgcn_fence(__ATOMIC_RELEASE, "agent");
            __hip_atomic_store(&flags[bid], epoch, __ATOMIC_RELAXED, __HIP_MEMORY_SCOPE_AGENT);
        }

        // ---- overlap barrier latency: intensity GEMM for t = p-1 (h already published)
        if (ct < 8 && p >= 1) {
            lam_eval(r0 + ct * 8 + (tid >> 5), p - 1, tid & 31, out_hid, Wi, bi, out_int);
        }

        // ---- barrier wait: thread t watches block t's flag
        while (__hip_atomic_load(&flags[tid], __ATOMIC_RELAXED, __HIP_MEMORY_SCOPE_AGENT) < epoch)
            __builtin_amdgcn_s_sleep(1);
        __builtin_amdgcn_fence(__ATOMIC_ACQUIRE, "agent");
        __syncthreads();
    }

    // final intensities for t = T-1 (uses h after last step)
    if (ct < 8) {
        lam_eval(r0 + ct * 8 + (tid >> 5), Tt - 1, tid & 31, out_hid, Wi, bi, out_int);
    }
}

extern "C" void kernel_launch(void* const* d_in, const int* in_sizes, int n_in,
                              void* d_out, int out_size, void* d_ws, size_t ws_size,
                              hipStream_t stream) {
    const int*   events = (const int*)d_in[0];
    const float* times  = (const float*)d_in[1];
    const float* emb    = (const float*)d_in[2];
    const float* Wg     = (const float*)d_in[3];
    const float* bg     = (const float*)d_in[4];
    const float* Wi     = (const float*)d_in[5];
    const float* bi     = (const float*)d_in[6];
    float* out_int = (float*)d_out;
    float* out_hid = out_int + (size_t)Bb * Tt * Ee;
    unsigned* flags = (unsigned*)d_ws;

    hipMemsetAsync(flags, 0, NBLK * sizeof(unsigned), stream);
    hipLaunchKernelGGL(nhp_main, dim3(NBLK), dim3(NTHR), 0, stream,
                       events, times, emb, Wg, bg, Wi, bi, out_int, out_hid, flags);
}

// Round 2
// 9475.906 us; speedup vs baseline: 2.4565x; 2.4565x over previous
//
#include <hip/hip_runtime.h>
#include <hip/hip_bf16.h>
#include <math.h>

// Neural Hawkes scan, MFMA edition. B=256,T=512,H=512,E=32.
// 256 blocks (16 row-tiles x 16 col-tiles), 256 thr (4 waves), 1 block/CU.
// Block owns 16 batch rows x 160 gate-cols (= 5 gates x 32 hcols).
// Wave (ks,ts): k-half ks*256..+256, tiles ts*5..+5 (tile=16 cols).
// Wh fragments fp16, PERMANENTLY register-resident (160 VGPR/lane).
// Per step: 8 A-frag loads + 40 MFMA + LDS reduce + thread-local gates.
// Grid barrier: per-block epoch flags (validated in R1).

#define Bb   256
#define Tt   512
#define Hh   512
#define Ee   32
#define G5H  2560
#define NBLK 256
#define NTHR 256
#define RT   16
#define CT   32

typedef __attribute__((ext_vector_type(8))) short f16x8;
typedef __attribute__((ext_vector_type(4))) float f32x4;

__device__ __forceinline__ float softplusf(float x) {
    return fmaxf(x, 0.f) + __logf(1.f + __expf(-fabsf(x)));
}
__device__ __forceinline__ float fast_tanh(float x) {
    const float t = fminf(fmaxf(x, -15.f), 15.f);
    const float e = __expf(2.f * t);
    return (e - 1.f) / (e + 1.f);
}
__device__ __forceinline__ unsigned short f2h(float f) {
    _Float16 h = (_Float16)f;
    return *reinterpret_cast<unsigned short*>(&h);
}

__device__ __forceinline__ void lam_step(int rlam, int t,
        const float* __restrict__ out_hid, const float* __restrict__ Wi,
        const float* __restrict__ bi, float* __restrict__ out_int,
        float (&lred)[8][Ee], int tid) {
    const float* hp = out_hid + ((size_t)rlam * Tt + t) * Hh;
    const int e = tid & 31, seg = tid >> 5;
    const float* wp = Wi + e;
    float a = 0.f;
    #pragma unroll 4
    for (int k = seg * 64; k < seg * 64 + 64; k += 4) {
        const float4 hv = *(const float4*)(hp + k);
        a += hv.x * wp[(size_t)k * Ee]       + hv.y * wp[(size_t)(k + 1) * Ee]
           + hv.z * wp[(size_t)(k + 2) * Ee] + hv.w * wp[(size_t)(k + 3) * Ee];
    }
    lred[seg][e] = a;
    __syncthreads();
    if (tid < Ee) {
        float s = bi[tid];
        #pragma unroll
        for (int i = 0; i < 8; ++i) s += lred[i][tid];
        out_int[((size_t)rlam * Tt + t) * Ee + tid] = softplusf(s);
    }
}

__global__ __launch_bounds__(NTHR, 1)
void nhp_main(const int* __restrict__ events, const float* __restrict__ times,
              const float* __restrict__ emb, const float* __restrict__ Wg,
              const float* __restrict__ bg, const float* __restrict__ Wi,
              const float* __restrict__ bi, float* __restrict__ out_int,
              float* __restrict__ out_hid, unsigned* __restrict__ flags,
              unsigned short* __restrict__ hb) {
    __shared__ float red[2][10][16][20];   // [ksplit][tile][col][row+pad] 25.6 KB
    __shared__ float gx[Ee][5][CT];        // x@Wx + b per event type, 20 KB
    __shared__ float lred[8][Ee];
    __shared__ int   ev_s[RT];
    __shared__ float dt_s[RT];

    const int tid  = threadIdx.x, bid = blockIdx.x;
    const int ct   = bid & 15;       // col tile (hcols ct*32..+32)
    const int rt   = bid >> 4;       // row tile
    const int r0   = rt * RT;
    const int lane = tid & 63;
    const int wv   = tid >> 6;
    const int ks   = wv & 1;         // k half
    const int ts   = wv >> 1;        // tile set
    const int frow = lane & 15;      // A-row / B-col within tile
    const int kgrp = lane >> 4;      // 0..3 (k sub-group of 8)

    // ---- one-time: gx[e][g][hc] = emb[e] @ Wx[:,col] + b  (5120 dots)
    for (int u = tid; u < Ee * 5 * CT; u += NTHR) {
        const int e = u / 160, r = u - e * 160;
        const int g = r >> 5, hc = r & 31;
        const int gcol = g * Hh + ct * CT + hc;
        float acc = bg[gcol];
        const float* er = emb + (size_t)e * Hh;
        for (int k = 0; k < Hh; k += 4) {
            acc += er[k]     * Wg[(size_t)k       * G5H + gcol];
            acc += er[k + 1] * Wg[(size_t)(k + 1) * G5H + gcol];
            acc += er[k + 2] * Wg[(size_t)(k + 2) * G5H + gcol];
            acc += er[k + 3] * Wg[(size_t)(k + 3) * G5H + gcol];
        }
        gx[e][g][hc] = acc;
    }

    // ---- one-time: Wh fp16 B-fragments into registers (stay for all T steps)
    f16x8 Bf[5][8];
    #pragma unroll
    for (int n = 0; n < 5; ++n) {
        const int tl  = ts * 5 + n;
        const int g   = tl >> 1, sub = tl & 1;
        const int col = g * Hh + ct * CT + sub * 16 + frow;
        #pragma unroll
        for (int kk = 0; kk < 8; ++kk) {
            const int k0 = ks * 256 + kk * 32 + kgrp * 8;
            union { f16x8 v; unsigned u[4]; } tmp;
            #pragma unroll
            for (int r = 0; r < 4; ++r) {
                const float w0 = Wg[(size_t)(Hh + k0 + 2 * r)     * G5H + col];
                const float w1 = Wg[(size_t)(Hh + k0 + 2 * r + 1) * G5H + col];
                tmp.u[r] = (unsigned)f2h(w0) | ((unsigned)f2h(w1) << 16);
            }
            Bf[n][kk] = tmp.v;
        }
    }

    float cst0 = 0.f, cst1 = 0.f;
    __syncthreads();

    unsigned epoch = 0;
    for (int p = 0; p < Tt; ++p) {
        if (tid < RT) {
            const int b = r0 + tid;
            ev_s[tid] = events[b * Tt + p];
            const float tp = times[b * Tt + p];
            dt_s[tid] = (p == 0) ? tp : tp - times[b * Tt + p - 1];
        }
        __syncthreads();

        if (p > 0) {  // h_0 = 0 -> GEMM only for p >= 1
            const unsigned short* hprev = hb + (size_t)((p - 1) & 1) * Bb * Hh;
            const size_t abase = (size_t)(r0 + frow) * Hh + ks * 256 + kgrp * 8;
            f16x8 a[8];
            #pragma unroll
            for (int kk = 0; kk < 8; ++kk)
                a[kk] = *(const f16x8*)(hprev + abase + kk * 32);
            f32x4 acc[5];
            #pragma unroll
            for (int n = 0; n < 5; ++n) acc[n] = (f32x4){0.f, 0.f, 0.f, 0.f};
            #pragma unroll
            for (int kk = 0; kk < 8; ++kk) {
                #pragma unroll
                for (int n = 0; n < 5; ++n)
                    acc[n] = __builtin_amdgcn_mfma_f32_16x16x32_f16(
                        a[kk], Bf[n][kk], acc[n], 0, 0, 0);
            }
            #pragma unroll
            for (int n = 0; n < 5; ++n)
                *(f32x4*)&red[ks][ts * 5 + n][frow][kgrp * 4] = acc[n];
        }
        __syncthreads();

        // ---- elementwise: thread handles 2 (row,hcol) pairs
        #pragma unroll
        for (int q = 0; q < 2; ++q) {
            const int pidx = tid + q * NTHR;
            const int hc = pidx & 31, row = pidx >> 5;
            const int e = ev_s[row];
            float g[5];
            #pragma unroll
            for (int gt = 0; gt < 5; ++gt) {
                const int tl = gt * 2 + (hc >> 4);
                float v = gx[e][gt][hc];
                if (p > 0)
                    v += red[0][tl][hc & 15][row] + red[1][tl][hc & 15][row];
                g[gt] = v;
            }
            const float ig  = fast_tanh(g[0]);
            const float fg  = fast_tanh(g[1]);
            const float og  = fast_tanh(g[2]);
            const float ctl = fast_tanh(g[3]);
            const float dec = softplusf(g[4]);
            const float cpv = q ? cst1 : cst0;
            const float cdec = cpv * __expf(-dec * dt_s[row]);
            const float cn = fg * cdec + ig * ctl;
            if (q) cst1 = cn; else cst0 = cn;
            const float hn = og * fast_tanh(cn);
            const int grow = r0 + row, gcol = ct * CT + hc;
            out_hid[((size_t)grow * Tt + p) * Hh + gcol] = hn;
            hb[(size_t)(p & 1) * Bb * Hh + (size_t)grow * Hh + gcol] = f2h(hn);
        }

        // ---- barrier arrive (release this step's h writes)
        __syncthreads();
        ++epoch;
        if (tid == 0) {
            __builtin_amdgcn_fence(__ATOMIC_RELEASE, "agent");
            __hip_atomic_store(&flags[bid], epoch, __ATOMIC_RELAXED, __HIP_MEMORY_SCOPE_AGENT);
        }

        // ---- overlap barrier latency: intensities for t = p-1 (row r0+ct)
        if (p >= 1)
            lam_step(r0 + ct, p - 1, out_hid, Wi, bi, out_int, lred, tid);

        // ---- barrier wait
        while (__hip_atomic_load(&flags[tid], __ATOMIC_RELAXED, __HIP_MEMORY_SCOPE_AGENT) < epoch)
            __builtin_amdgcn_s_sleep(1);
        __builtin_amdgcn_fence(__ATOMIC_ACQUIRE, "agent");
        __syncthreads();
    }

    // final intensities for t = T-1
    lam_step(r0 + ct, Tt - 1, out_hid, Wi, bi, out_int, lred, tid);
}

extern "C" void kernel_launch(void* const* d_in, const int* in_sizes, int n_in,
                              void* d_out, int out_size, void* d_ws, size_t ws_size,
                              hipStream_t stream) {
    const int*   events = (const int*)d_in[0];
    const float* times  = (const float*)d_in[1];
    const float* emb    = (const float*)d_in[2];
    const float* Wg     = (const float*)d_in[3];
    const float* bg     = (const float*)d_in[4];
    const float* Wi     = (const float*)d_in[5];
    const float* bi     = (const float*)d_in[6];
    float* out_int = (float*)d_out;
    float* out_hid = out_int + (size_t)Bb * Tt * Ee;
    unsigned* flags = (unsigned*)d_ws;
    unsigned short* hb = (unsigned short*)((char*)d_ws + 1024);  // 2x256x512 fp16

    hipMemsetAsync(flags, 0, NBLK * sizeof(unsigned), stream);
    hipLaunchKernelGGL(nhp_main, dim3(NBLK), dim3(NTHR), 0, stream,
                       events, times, emb, Wg, bg, Wi, bi, out_int, out_hid,
                       flags, hb);
}

// Round 3
// 3492.327 us; speedup vs baseline: 6.6653x; 2.7133x over previous
//
#include <hip/hip_runtime.h>
#include <math.h>

// Neural Hawkes scan. B=256,T=512,H=512,E=32.
// Kernel A (scan): 256 blocks = 16 row-tiles x 16 col-tiles, 256 thr (4 waves).
//   Block owns 16 batch rows x 160 gate-cols; Wh fp16 register-resident.
//   Cross-block h exchange via sc0sc1 (L3-coherent) asm loads/stores; barrier
//   scoped to the 16 blocks of a row-tile (the only true data dependency).
// Kernel B (intensities): fully parallel softplus(h @ W_int + b) afterwards.

#define Bb   256
#define Tt   512
#define Hh   512
#define Ee   32
#define G5H  2560
#define NTHR 256
#define RT   16
#define CT   32

typedef __attribute__((ext_vector_type(8))) short f16x8;
typedef __attribute__((ext_vector_type(4))) float f32x4;

__device__ __forceinline__ float softplusf(float x) {
    return fmaxf(x, 0.f) + __logf(1.f + __expf(-fabsf(x)));
}
__device__ __forceinline__ float fast_tanh(float x) {
    const float t = fminf(fmaxf(x, -15.f), 15.f);
    const float e = __expf(2.f * t);
    return (e - 1.f) / (e + 1.f);
}
__device__ __forceinline__ unsigned short f2h(float f) {
    _Float16 h = (_Float16)f;
    return *reinterpret_cast<unsigned short*>(&h);
}

// 8x 16B L3-coherent loads (bypass L1/L2), chunks 64B apart, then drain.
__device__ __forceinline__ void load_a8(const unsigned short* p, f16x8 (&a)[8]) {
    asm volatile(
        "global_load_dwordx4 %0, %8, off sc0 sc1\n\t"
        "global_load_dwordx4 %1, %8, off offset:64 sc0 sc1\n\t"
        "global_load_dwordx4 %2, %8, off offset:128 sc0 sc1\n\t"
        "global_load_dwordx4 %3, %8, off offset:192 sc0 sc1\n\t"
        "global_load_dwordx4 %4, %8, off offset:256 sc0 sc1\n\t"
        "global_load_dwordx4 %5, %8, off offset:320 sc0 sc1\n\t"
        "global_load_dwordx4 %6, %8, off offset:384 sc0 sc1\n\t"
        "global_load_dwordx4 %7, %8, off offset:448 sc0 sc1\n\t"
        "s_waitcnt vmcnt(0)"
        : "=&v"(a[0]), "=&v"(a[1]), "=&v"(a[2]), "=&v"(a[3]),
          "=&v"(a[4]), "=&v"(a[5]), "=&v"(a[6]), "=&v"(a[7])
        : "v"(p) : "memory");
}
__device__ __forceinline__ void store_u32_sc(void* p, unsigned v) {
    asm volatile("global_store_dword %0, %1, off sc0 sc1"
                 :: "v"(p), "v"(v) : "memory");
}

__global__ __launch_bounds__(NTHR, 1)
void nhp_scan(const int* __restrict__ events, const float* __restrict__ times,
              const float* __restrict__ emb, const float* __restrict__ Wg,
              const float* __restrict__ bg, float* __restrict__ out_hid,
              unsigned* __restrict__ flags, unsigned short* __restrict__ hb) {
    __shared__ float red[2][10][16][20];   // [ksplit][tile][col][row+pad] 25.6 KB
    __shared__ float gx[Ee][5][34];        // padded: kills 4-way conflicts, 21.8 KB
    __shared__ int   ev_s[RT];
    __shared__ float dt_s[RT];

    const int tid  = threadIdx.x, bid = blockIdx.x;
    const int rt   = bid & 15;        // row tile: peers share rt
    const int ct   = bid >> 4;        // col tile
    const int r0   = rt * RT;
    const int lane = tid & 63, wv = tid >> 6;
    const int ks   = wv & 1, ts = wv >> 1;
    const int frow = lane & 15, kgrp = lane >> 4;
    const int erow = tid >> 4;        // elementwise: row 0..15
    const int ecp  = (tid & 15) * 2;  // elementwise: 2 adjacent cols

    // ---- one-time: gx[e][g][hc] = emb[e] @ Wx[:,col] + b
    for (int u = tid; u < Ee * 5 * CT; u += NTHR) {
        const int e = u / 160, r = u - e * 160;
        const int g = r >> 5, hc = r & 31;
        const int gcol = g * Hh + ct * CT + hc;
        float acc = bg[gcol];
        const float* er = emb + (size_t)e * Hh;
        for (int k = 0; k < Hh; k += 4) {
            acc += er[k]     * Wg[(size_t)k       * G5H + gcol];
            acc += er[k + 1] * Wg[(size_t)(k + 1) * G5H + gcol];
            acc += er[k + 2] * Wg[(size_t)(k + 2) * G5H + gcol];
            acc += er[k + 3] * Wg[(size_t)(k + 3) * G5H + gcol];
        }
        gx[e][g][hc] = acc;
    }

    // ---- one-time: Wh fp16 B-fragments, register-resident for all T steps
    f16x8 Bf[5][8];
    #pragma unroll
    for (int n = 0; n < 5; ++n) {
        const int tl  = ts * 5 + n;
        const int g   = tl >> 1, sub = tl & 1;
        const int col = g * Hh + ct * CT + sub * 16 + frow;
        #pragma unroll
        for (int kk = 0; kk < 8; ++kk) {
            const int k0 = ks * 256 + kk * 32 + kgrp * 8;
            union { f16x8 v; unsigned u[4]; } tmp;
            #pragma unroll
            for (int r = 0; r < 4; ++r) {
                const float w0 = Wg[(size_t)(Hh + k0 + 2 * r)     * G5H + col];
                const float w1 = Wg[(size_t)(Hh + k0 + 2 * r + 1) * G5H + col];
                tmp.u[r] = (unsigned)f2h(w0) | ((unsigned)f2h(w1) << 16);
            }
            Bf[n][kk] = tmp.v;
        }
    }

    float cA = 0.f, cB = 0.f;
    __syncthreads();

    unsigned epoch = 0;
    for (int p = 0; p < Tt; ++p) {
        if (tid < RT) {
            const int b = r0 + tid;
            ev_s[tid] = events[b * Tt + p];
            const float tp = times[b * Tt + p];
            dt_s[tid] = (p == 0) ? tp : tp - times[b * Tt + p - 1];
        }

        if (p > 0) {  // gate GEMM vs h_{p-1} (peers' data published, L3-coherent)
            const unsigned short* hprev = hb + (size_t)((p - 1) & 1) * Bb * Hh
                                        + (size_t)(r0 + frow) * Hh + ks * 256 + kgrp * 8;
            f16x8 a[8];
            load_a8(hprev, a);
            f32x4 acc[5];
            #pragma unroll
            for (int n = 0; n < 5; ++n) acc[n] = (f32x4){0.f, 0.f, 0.f, 0.f};
            #pragma unroll
            for (int kk = 0; kk < 8; ++kk) {
                #pragma unroll
                for (int n = 0; n < 5; ++n)
                    acc[n] = __builtin_amdgcn_mfma_f32_16x16x32_f16(
                        a[kk], Bf[n][kk], acc[n], 0, 0, 0);
            }
            #pragma unroll
            for (int n = 0; n < 5; ++n)
                *(f32x4*)&red[ks][ts * 5 + n][frow][kgrp * 4] = acc[n];
        }
        __syncthreads();

        // ---- elementwise: thread = (row erow, cols ecp, ecp+1)
        const int   e  = ev_s[erow];
        const float dt = dt_s[erow];
        float hn[2];
        {
            float v[2][5];
            #pragma unroll
            for (int gt = 0; gt < 5; ++gt) {
                const int tl = gt * 2 + (ecp >> 4);
                v[0][gt] = gx[e][gt][ecp];
                v[1][gt] = gx[e][gt][ecp + 1];
                if (p > 0) {
                    const int fr = ecp & 15;
                    v[0][gt] += red[0][tl][fr][erow]     + red[1][tl][fr][erow];
                    v[1][gt] += red[0][tl][fr + 1][erow] + red[1][tl][fr + 1][erow];
                }
            }
            #pragma unroll
            for (int q = 0; q < 2; ++q) {
                const float ig  = fast_tanh(v[q][0]);
                const float fg  = fast_tanh(v[q][1]);
                const float og  = fast_tanh(v[q][2]);
                const float ctl = fast_tanh(v[q][3]);
                const float dec = softplusf(v[q][4]);
                const float cpv = q ? cB : cA;
                const float cn  = fg * (cpv * __expf(-dec * dt)) + ig * ctl;
                if (q) cB = cn; else cA = cn;
                hn[q] = og * fast_tanh(cn);
            }
        }

        // publish h (fp16 pair, L3-coherent) — the only cross-block data
        const unsigned pk = (unsigned)f2h(hn[0]) | ((unsigned)f2h(hn[1]) << 16);
        store_u32_sc(hb + (size_t)(p & 1) * Bb * Hh
                        + (size_t)(r0 + erow) * Hh + ct * CT + ecp, pk);
        asm volatile("s_waitcnt vmcnt(0)" ::: "memory");  // h visible at L3
        __syncthreads();                                   // all waves drained
        ++epoch;
        if (tid == 0)
            __hip_atomic_store(&flags[bid], epoch, __ATOMIC_RELAXED,
                               __HIP_MEMORY_SCOPE_AGENT);

        // out_hid (fp32 output) — off the critical chain
        float2 ho; ho.x = hn[0]; ho.y = hn[1];
        *(float2*)(out_hid + ((size_t)(r0 + erow) * Tt + p) * Hh + ct * CT + ecp) = ho;

        // wait only for the 15 peers of this row-tile
        if (tid < 16) {
            const unsigned* f = &flags[tid * 16 + rt];
            while (__hip_atomic_load(f, __ATOMIC_RELAXED,
                                     __HIP_MEMORY_SCOPE_AGENT) < epoch)
                __builtin_amdgcn_s_sleep(1);
        }
        __syncthreads();
    }
}

// out_int[row,e] = softplus(out_hid[row,:] @ Wi + bi), row = b*T + t flat.
__global__ __launch_bounds__(NTHR)
void nhp_intens(const float* __restrict__ out_hid, const float* __restrict__ Wi,
                const float* __restrict__ bi, float* __restrict__ out_int) {
    __shared__ float lred[8][8][32];
    const int tid = threadIdx.x;
    const int seg = tid >> 5, e = tid & 31;
    const size_t row0 = (size_t)blockIdx.x * 8;

    float w[64];
    #pragma unroll
    for (int j = 0; j < 64; ++j) w[j] = Wi[(size_t)(seg * 64 + j) * Ee + e];

    #pragma unroll
    for (int r = 0; r < 8; ++r) {
        const float* hp = out_hid + (row0 + r) * Hh + seg * 64;
        float a0 = 0.f, a1 = 0.f;
        #pragma unroll
        for (int k = 0; k < 64; k += 4) {
            const float4 hv = *(const float4*)(hp + k);
            a0 += hv.x * w[k]     + hv.y * w[k + 1];
            a1 += hv.z * w[k + 2] + hv.w * w[k + 3];
        }
        lred[r][seg][e] = a0 + a1;
    }
    __syncthreads();
    const int rr = tid >> 5;
    float s = bi[e];
    #pragma unroll
    for (int i = 0; i < 8; ++i) s += lred[rr][i][e];
    out_int[(row0 + rr) * Ee + e] = softplusf(s);
}

extern "C" void kernel_launch(void* const* d_in, const int* in_sizes, int n_in,
                              void* d_out, int out_size, void* d_ws, size_t ws_size,
                              hipStream_t stream) {
    const int*   events = (const int*)d_in[0];
    const float* times  = (const float*)d_in[1];
    const float* emb    = (const float*)d_in[2];
    const float* Wg     = (const float*)d_in[3];
    const float* bg     = (const float*)d_in[4];
    const float* Wi     = (const float*)d_in[5];
    const float* bi     = (const float*)d_in[6];
    float* out_int = (float*)d_out;
    float* out_hid = out_int + (size_t)Bb * Tt * Ee;
    unsigned* flags = (unsigned*)d_ws;
    unsigned short* hb = (unsigned short*)((char*)d_ws + 1024);  // 2x256x512 fp16

    hipMemsetAsync(flags, 0, 256 * sizeof(unsigned), stream);
    hipLaunchKernelGGL(nhp_scan, dim3(256), dim3(NTHR), 0, stream,
                       events, times, emb, Wg, bg, out_hid, flags, hb);
    hipLaunchKernelGGL(nhp_intens, dim3((Bb * Tt) / 8), dim3(NTHR), 0, stream,
                       out_hid, Wi, bi, out_int);
}

// Round 5
// 2527.092 us; speedup vs baseline: 9.2112x; 1.3820x over previous
//
#include <hip/hip_runtime.h>
#include <math.h>

// Neural Hawkes scan. B=256,T=512,H=512,E=32.
// 256 blocks = 16 row-groups x 16 col-tiles, 256 thr (4 waves), 1 block/CU.
// Memory protocol (R3-proven): hb (fp16 h, double-buffered) via sc0 sc1
// asm loads/stores (L3-coherent, placement-independent); sync via
// __hip_atomic_* agent-scope intrinsics. NO XCD assumptions (R4 hang).
// Barrier: per-group arrive counter (atomicAdd by tid0 after drain); tid0
// polls one word >= 16*(p+1). Watchdog on every poll: break, never hang.
// Wh fp16 register-resident: Bf[10][4] = 160 VGPR/lane; 4-way K-split,
// no duplicate hb reads; conflict-free red layout (<=2-way, free).

#define Bb   256
#define Tt   512
#define Hh   512
#define Ee   32
#define G5H  2560
#define NTHR 256
#define RT   16
#define CT   32

typedef __attribute__((ext_vector_type(8))) short f16x8;
typedef __attribute__((ext_vector_type(4))) float f32x4;

__device__ __forceinline__ float softplusf(float x) {
    return fmaxf(x, 0.f) + __logf(1.f + __expf(-fabsf(x)));
}
__device__ __forceinline__ float fast_tanh(float x) {
    const float t = fminf(fmaxf(x, -15.f), 15.f);
    const float e = __expf(2.f * t);
    return (e - 1.f) / (e + 1.f);
}
__device__ __forceinline__ unsigned short f2h(float f) {
    _Float16 h = (_Float16)f;
    return *reinterpret_cast<unsigned short*>(&h);
}

// 4x 16B L3-coherent loads (bypass L1/L2), 64B apart, then drain. (R3-proven)
__device__ __forceinline__ void load_a4(const unsigned short* p, f16x8 (&a)[4]) {
    asm volatile(
        "global_load_dwordx4 %0, %4, off sc0 sc1\n\t"
        "global_load_dwordx4 %1, %4, off offset:64 sc0 sc1\n\t"
        "global_load_dwordx4 %2, %4, off offset:128 sc0 sc1\n\t"
        "global_load_dwordx4 %3, %4, off offset:192 sc0 sc1\n\t"
        "s_waitcnt vmcnt(0)"
        : "=&v"(a[0]), "=&v"(a[1]), "=&v"(a[2]), "=&v"(a[3])
        : "v"(p) : "memory");
}
__device__ __forceinline__ void st_u32_sc(void* p, unsigned v) {
    asm volatile("global_store_dword %0, %1, off sc0 sc1"
                 :: "v"(p), "v"(v) : "memory");
}

__global__ __launch_bounds__(NTHR, 1)
void nhp_scan(const int* __restrict__ events, const float* __restrict__ times,
              const float* __restrict__ emb, const float* __restrict__ Wg,
              const float* __restrict__ bg, float* __restrict__ out_hid,
              unsigned* __restrict__ cnt, unsigned short* __restrict__ hb) {
    __shared__ float red[4][10][16][18];   // [ksplit][tile][b-row][g-col+pad] 46 KB
    __shared__ float gx[Ee][5][34];        // x@Wx + b per event type, 21.8 KB
    __shared__ int   ev_s[RT];
    __shared__ float dt_s[RT];

    const int tid  = threadIdx.x, bid = blockIdx.x;
    const int rt   = bid & 15;        // row group: peers share rt (R3 mapping)
    const int ct   = bid >> 4;        // col tile
    const int r0   = rt * RT;
    const int lane = tid & 63;
    const int ks   = tid >> 6;        // 4-way K split: k in [ks*128, +128)
    const int frow = lane & 15, kgrp = lane >> 4;
    const int erow = tid >> 4;        // elementwise row 0..15
    const int ecp  = (tid & 15) * 2;  // elementwise col pair

    // ---- one-time: gx[e][g][hc] = emb[e] @ Wx[:,col] + b
    for (int u = tid; u < Ee * 5 * CT; u += NTHR) {
        const int e = u / 160, r = u - e * 160;
        const int g = r >> 5, hc = r & 31;
        const int gcol = g * Hh + ct * CT + hc;
        float acc = bg[gcol];
        const float* er = emb + (size_t)e * Hh;
        for (int k = 0; k < Hh; k += 4) {
            acc += er[k]     * Wg[(size_t)k       * G5H + gcol];
            acc += er[k + 1] * Wg[(size_t)(k + 1) * G5H + gcol];
            acc += er[k + 2] * Wg[(size_t)(k + 2) * G5H + gcol];
            acc += er[k + 3] * Wg[(size_t)(k + 3) * G5H + gcol];
        }
        gx[e][g][hc] = acc;
    }

    // ---- one-time: Wh fp16 B-fragments, register-resident for all T steps
    f16x8 Bf[10][4];
    #pragma unroll
    for (int n = 0; n < 10; ++n) {
        const int col = (n >> 1) * Hh + ct * CT + (n & 1) * 16 + frow;
        #pragma unroll
        for (int kk = 0; kk < 4; ++kk) {
            const int k0 = ks * 128 + kk * 32 + kgrp * 8;
            union { f16x8 v; unsigned u[4]; } tmp;
            #pragma unroll
            for (int r = 0; r < 4; ++r) {
                const float w0 = Wg[(size_t)(Hh + k0 + 2 * r)     * G5H + col];
                const float w1 = Wg[(size_t)(Hh + k0 + 2 * r + 1) * G5H + col];
                tmp.u[r] = (unsigned)f2h(w0) | ((unsigned)f2h(w1) << 16);
            }
            Bf[n][kk] = tmp.v;
        }
    }

    float cA = 0.f, cB = 0.f;
    __syncthreads();

    for (int p = 0; p < Tt; ++p) {
        if (tid < RT) {
            const int b = r0 + tid;
            ev_s[tid] = events[b * Tt + p];
            const float tp = times[b * Tt + p];
            dt_s[tid] = (p == 0) ? tp : tp - times[b * Tt + p - 1];
        }

        if (p > 0) {  // gate GEMM vs h_{p-1}
            const unsigned short* hprev = hb + (size_t)((p - 1) & 1) * Bb * Hh
                                        + (size_t)(r0 + frow) * Hh + ks * 128 + kgrp * 8;
            f16x8 a[4];
            load_a4(hprev, a);
            f32x4 acc[10];
            #pragma unroll
            for (int n = 0; n < 10; ++n) acc[n] = (f32x4){0.f, 0.f, 0.f, 0.f};
            #pragma unroll
            for (int kk = 0; kk < 4; ++kk) {
                #pragma unroll
                for (int n = 0; n < 10; ++n)
                    acc[n] = __builtin_amdgcn_mfma_f32_16x16x32_f16(
                        a[kk], Bf[n][kk], acc[n], 0, 0, 0);
            }
            #pragma unroll
            for (int n = 0; n < 10; ++n)
                #pragma unroll
                for (int r = 0; r < 4; ++r)
                    red[ks][n][kgrp * 4 + r][frow] = acc[n][r];
        }
        __syncthreads();

        // ---- elementwise: thread = (row erow, cols ecp, ecp+1)
        const int   e  = ev_s[erow];
        const float dt = dt_s[erow];
        float hn[2];
        {
            float v0[5], v1[5];
            const int tl0 = ecp >> 4, fc = ecp & 15;
            #pragma unroll
            for (int gt = 0; gt < 5; ++gt) {
                const float2 gv = *(const float2*)&gx[e][gt][ecp];
                v0[gt] = gv.x; v1[gt] = gv.y;
                if (p > 0) {
                    const int tl = gt * 2 + tl0;
                    #pragma unroll
                    for (int s = 0; s < 4; ++s) {
                        const float2 pr = *(const float2*)&red[s][tl][erow][fc];
                        v0[gt] += pr.x; v1[gt] += pr.y;
                    }
                }
            }
            #pragma unroll
            for (int q = 0; q < 2; ++q) {
                const float* v = q ? v1 : v0;
                const float ig  = fast_tanh(v[0]);
                const float fg  = fast_tanh(v[1]);
                const float og  = fast_tanh(v[2]);
                const float ctl = fast_tanh(v[3]);
                const float dec = softplusf(v[4]);
                const float cpv = q ? cB : cA;
                const float cn  = fg * (cpv * __expf(-dec * dt)) + ig * ctl;
                if (q) cB = cn; else cA = cn;
                hn[q] = og * fast_tanh(cn);
            }
        }

        // publish h (fp16 pair, L3) — the only cross-block data
        const unsigned pk = (unsigned)f2h(hn[0]) | ((unsigned)f2h(hn[1]) << 16);
        st_u32_sc(hb + (size_t)(p & 1) * Bb * Hh
                     + (size_t)(r0 + erow) * Hh + ct * CT + ecp, pk);
        asm volatile("s_waitcnt vmcnt(0)" ::: "memory");  // h acked at L3
        __syncthreads();                                   // all waves drained

        // arrive: one agent-scope atomic per block (fire-and-forget)
        if (tid == 0)
            (void)__hip_atomic_fetch_add(&cnt[rt * 16], 1u, __ATOMIC_RELAXED,
                                         __HIP_MEMORY_SCOPE_AGENT);

        // fp32 output store — off the critical chain
        float2 ho; ho.x = hn[0]; ho.y = hn[1];
        *(float2*)(out_hid + ((size_t)(r0 + erow) * Tt + p) * Hh + ct * CT + ecp) = ho;

        // wait: tid0 polls one word; watchdog breaks instead of hanging
        if (tid == 0) {
            const unsigned target = 16u * (unsigned)(p + 1);
            int guard = 0;
            while (__hip_atomic_load(&cnt[rt * 16], __ATOMIC_RELAXED,
                                     __HIP_MEMORY_SCOPE_AGENT) < target) {
                if (++guard > 2000000) break;   // never hang the bench
            }
        }
        __syncthreads();
    }
}

// out_int[row,e] = softplus(out_hid[row,:] @ Wi + bi), 32 rows per block.
__global__ __launch_bounds__(NTHR)
void nhp_intens(const float* __restrict__ out_hid, const float* __restrict__ Wi,
                const float* __restrict__ bi, float* __restrict__ out_int) {
    __shared__ float lred[32][8][32];
    const int tid = threadIdx.x;
    const int seg = tid >> 5, e = tid & 31;
    const size_t row0 = (size_t)blockIdx.x * 32;

    float w[64];
    #pragma unroll
    for (int j = 0; j < 64; ++j) w[j] = Wi[(size_t)(seg * 64 + j) * Ee + e];

    for (int r = 0; r < 32; ++r) {
        const float* hp = out_hid + (row0 + r) * Hh + seg * 64;
        float a0 = 0.f, a1 = 0.f;
        #pragma unroll
        for (int k = 0; k < 64; k += 4) {
            const float4 hv = *(const float4*)(hp + k);
            a0 += hv.x * w[k]     + hv.y * w[k + 1];
            a1 += hv.z * w[k + 2] + hv.w * w[k + 3];
        }
        lred[r][seg][e] = a0 + a1;
    }
    __syncthreads();
    #pragma unroll
    for (int c = 0; c < 4; ++c) {
        const int r = c * 8 + (tid >> 5);
        float s = bi[e];
        #pragma unroll
        for (int i = 0; i < 8; ++i) s += lred[r][i][e];
        out_int[(row0 + r) * Ee + e] = softplusf(s);
    }
}

extern "C" void kernel_launch(void* const* d_in, const int* in_sizes, int n_in,
                              void* d_out, int out_size, void* d_ws, size_t ws_size,
                              hipStream_t stream) {
    const int*   events = (const int*)d_in[0];
    const float* times  = (const float*)d_in[1];
    const float* emb    = (const float*)d_in[2];
    const float* Wg     = (const float*)d_in[3];
    const float* bg     = (const float*)d_in[4];
    const float* Wi     = (const float*)d_in[5];
    const float* bi     = (const float*)d_in[6];
    float* out_int = (float*)d_out;
    float* out_hid = out_int + (size_t)Bb * Tt * Ee;
    unsigned* cnt = (unsigned*)d_ws;                           // 16 groups x 64B
    unsigned short* hb = (unsigned short*)((char*)d_ws + 4096);// 2x256x512 fp16

    hipMemsetAsync(d_ws, 0, 4096, stream);
    hipLaunchKernelGGL(nhp_scan, dim3(256), dim3(NTHR), 0, stream,
                       events, times, emb, Wg, bg, out_hid, cnt, hb);
    hipLaunchKernelGGL(nhp_intens, dim3((Bb * Tt) / 32), dim3(NTHR), 0, stream,
                       out_hid, Wi, bi, out_int);
}

// Round 6
// 2469.083 us; speedup vs baseline: 9.4276x; 1.0235x over previous
//
#include <hip/hip_runtime.h>
#include <math.h>

// Neural Hawkes scan. B=256,T=512,H=512,E=32.
// 256 blocks = 16 row-groups x 16 col-tiles, 256 thr (4 waves), 1 block/CU.
// NO grid barrier: h published as tagged 8B units (fp16x2 data + step tag,
// single dwordx2 sc0sc1 store = 8B atomic). Consumer waves retry-load their
// K-slice until all tags match -> signal and data arrive in the SAME load.
// Drift bounded by the data dependency; hb double-buffered by parity (proof:
// a block at step p+2 has observed all peers' p+1 tags, which implies those
// peers consumed h_p). Watchdog on retry: break, never hang (R4 lesson).
// Wh fp16 register-resident (Bf[10][4]); 4-way K-split; gx XOR-swizzled.

#define Bb   256
#define Tt   512
#define Hh   512
#define Ee   32
#define G5H  2560
#define NTHR 256
#define RT   16
#define CT   32

typedef __attribute__((ext_vector_type(8))) short f16x8;
typedef __attribute__((ext_vector_type(4))) float f32x4;
typedef __attribute__((ext_vector_type(4))) unsigned u32x4;
typedef __attribute__((ext_vector_type(2))) unsigned u32x2;

__device__ __forceinline__ float softplusf(float x) {
    return fmaxf(x, 0.f) + __logf(1.f + __expf(-fabsf(x)));
}
__device__ __forceinline__ float fast_tanh(float x) {
    const float t = fminf(fmaxf(x, -15.f), 15.f);
    const float e = __expf(2.f * t);
    return (e - 1.f) / (e + 1.f);
}
__device__ __forceinline__ unsigned short f2h(float f) {
    _Float16 h = (_Float16)f;
    return *reinterpret_cast<unsigned short*>(&h);
}

// 8x 16B L3-coherent loads of tagged units: kk-th 32B at byte kk*128.
__device__ __forceinline__ void load_tagged8(const unsigned* p, u32x4 (&d)[8]) {
    asm volatile(
        "global_load_dwordx4 %0, %8, off sc0 sc1\n\t"
        "global_load_dwordx4 %1, %8, off offset:16 sc0 sc1\n\t"
        "global_load_dwordx4 %2, %8, off offset:128 sc0 sc1\n\t"
        "global_load_dwordx4 %3, %8, off offset:144 sc0 sc1\n\t"
        "global_load_dwordx4 %4, %8, off offset:256 sc0 sc1\n\t"
        "global_load_dwordx4 %5, %8, off offset:272 sc0 sc1\n\t"
        "global_load_dwordx4 %6, %8, off offset:384 sc0 sc1\n\t"
        "global_load_dwordx4 %7, %8, off offset:400 sc0 sc1\n\t"
        "s_waitcnt vmcnt(0)"
        : "=&v"(d[0]), "=&v"(d[1]), "=&v"(d[2]), "=&v"(d[3]),
          "=&v"(d[4]), "=&v"(d[5]), "=&v"(d[6]), "=&v"(d[7])
        : "v"(p) : "memory");
}
__device__ __forceinline__ void store_tagged(unsigned* p, unsigned data, unsigned tag) {
    u32x2 v; v.x = data; v.y = tag;
    asm volatile("global_store_dwordx2 %0, %1, off sc0 sc1"
                 :: "v"(p), "v"(v) : "memory");
}

__global__ __launch_bounds__(NTHR, 1)
void nhp_scan(const int* __restrict__ events, const float* __restrict__ times,
              const float* __restrict__ emb, const float* __restrict__ Wg,
              const float* __restrict__ bg, float* __restrict__ out_hid,
              unsigned* __restrict__ hb) {
    __shared__ float red[2][4][10][16][18];  // [par][ksplit][tile][row][col+pad] 92KB
    __shared__ float gx[Ee][5][34];          // col XOR-swizzled by (e&7)<<2
    __shared__ int   ev_s[2][RT];
    __shared__ float dt_s[2][RT];

    const int tid  = threadIdx.x, bid = blockIdx.x;
    const int rt   = bid & 15;        // row group
    const int ct   = bid >> 4;        // col tile
    const int r0   = rt * RT;
    const int lane = tid & 63;
    const int ks   = tid >> 6;        // 4-way K split: k in [ks*128, +128)
    const int frow = lane & 15, kgrp = lane >> 4;
    const int erow = tid >> 4;        // elementwise row 0..15
    const int ecp  = (tid & 15) * 2;  // elementwise col pair

    // ---- one-time: gx[e][g][hc] = emb[e] @ Wx[:,col] + b (XOR-swizzled store)
    for (int u = tid; u < Ee * 5 * CT; u += NTHR) {
        const int e = u / 160, r = u - e * 160;
        const int g = r >> 5, hc = r & 31;
        const int gcol = g * Hh + ct * CT + hc;
        float acc = bg[gcol];
        const float* er = emb + (size_t)e * Hh;
        for (int k = 0; k < Hh; k += 4) {
            acc += er[k]     * Wg[(size_t)k       * G5H + gcol];
            acc += er[k + 1] * Wg[(size_t)(k + 1) * G5H + gcol];
            acc += er[k + 2] * Wg[(size_t)(k + 2) * G5H + gcol];
            acc += er[k + 3] * Wg[(size_t)(k + 3) * G5H + gcol];
        }
        gx[e][g][hc ^ ((e & 7) << 2)] = acc;
    }

    // ---- one-time: Wh fp16 B-fragments, register-resident for all T steps
    f16x8 Bf[10][4];
    #pragma unroll
    for (int n = 0; n < 10; ++n) {
        const int col = (n >> 1) * Hh + ct * CT + (n & 1) * 16 + frow;
        #pragma unroll
        for (int kk = 0; kk < 4; ++kk) {
            const int k0 = ks * 128 + kk * 32 + kgrp * 8;
            union { f16x8 v; unsigned u[4]; } tmp;
            #pragma unroll
            for (int r = 0; r < 4; ++r) {
                const float w0 = Wg[(size_t)(Hh + k0 + 2 * r)     * G5H + col];
                const float w1 = Wg[(size_t)(Hh + k0 + 2 * r + 1) * G5H + col];
                tmp.u[r] = (unsigned)f2h(w0) | ((unsigned)f2h(w1) << 16);
            }
            Bf[n][kk] = tmp.v;
        }
    }

    float cA = 0.f, cB = 0.f;
    __syncthreads();

    for (int p = 0; p < Tt; ++p) {
        const int par = p & 1;
        if (tid < RT) {
            const int b = r0 + tid;
            ev_s[par][tid] = events[b * Tt + p];
            const float tp = times[b * Tt + p];
            dt_s[par][tid] = (p == 0) ? tp : tp - times[b * Tt + p - 1];
        }

        if (p > 0) {  // gate GEMM vs h_{p-1}: tagged retry-load IS the barrier
            const unsigned* base = hb + ((size_t)((p - 1) & 1) * Bb * 256
                                 + (size_t)(r0 + frow) * 256 + ks * 64 + kgrp * 4) * 2;
            const unsigned want = (unsigned)p;   // tag written at step p-1
            u32x4 d[8];
            int guard = 0;
            for (;;) {
                load_tagged8(base, d);
                int ok = 1;
                #pragma unroll
                for (int i = 0; i < 8; ++i)
                    ok &= (d[i].y == want) & (d[i].w == want);
                if (__all(ok)) break;
                if (++guard > 100000) break;     // never hang the bench
                __builtin_amdgcn_s_sleep(1);
            }
            f16x8 a[4];
            #pragma unroll
            for (int kk = 0; kk < 4; ++kk) {
                union { f16x8 v; unsigned u[4]; } t;
                t.u[0] = d[2 * kk].x;     t.u[1] = d[2 * kk].z;
                t.u[2] = d[2 * kk + 1].x; t.u[3] = d[2 * kk + 1].z;
                a[kk] = t.v;
            }
            f32x4 acc[10];
            #pragma unroll
            for (int n = 0; n < 10; ++n) acc[n] = (f32x4){0.f, 0.f, 0.f, 0.f};
            #pragma unroll
            for (int kk = 0; kk < 4; ++kk) {
                #pragma unroll
                for (int n = 0; n < 10; ++n)
                    acc[n] = __builtin_amdgcn_mfma_f32_16x16x32_f16(
                        a[kk], Bf[n][kk], acc[n], 0, 0, 0);
            }
            #pragma unroll
            for (int n = 0; n < 10; ++n)
                #pragma unroll
                for (int r = 0; r < 4; ++r)
                    red[par][ks][n][kgrp * 4 + r][frow] = acc[n][r];
        }
        __syncthreads();   // the ONLY per-step block sync

        // ---- elementwise: thread = (row erow, cols ecp, ecp+1)
        const int   e  = ev_s[par][erow];
        const float dt = dt_s[par][erow];
        const int   sc = (e & 7) << 2;
        float hn[2];
        {
            float v0[5], v1[5];
            const int tl0 = ecp >> 4, fc = ecp & 15;
            #pragma unroll
            for (int gt = 0; gt < 5; ++gt) {
                const float2 gv = *(const float2*)&gx[e][gt][ecp ^ sc];
                v0[gt] = gv.x; v1[gt] = gv.y;
                if (p > 0) {
                    const int tl = gt * 2 + tl0;
                    #pragma unroll
                    for (int s = 0; s < 4; ++s) {
                        const float2 pr = *(const float2*)&red[par][s][tl][erow][fc];
                        v0[gt] += pr.x; v1[gt] += pr.y;
                    }
                }
            }
            #pragma unroll
            for (int q = 0; q < 2; ++q) {
                const float* v = q ? v1 : v0;
                const float ig  = fast_tanh(v[0]);
                const float fg  = fast_tanh(v[1]);
                const float og  = fast_tanh(v[2]);
                const float ctl = fast_tanh(v[3]);
                const float dec = softplusf(v[4]);
                const float cpv = q ? cB : cA;
                const float cn  = fg * (cpv * __expf(-dec * dt)) + ig * ctl;
                if (q) cB = cn; else cA = cn;
                hn[q] = og * fast_tanh(cn);
            }
        }

        // publish tagged h: one 8B-atomic dwordx2 (data+tag) — no drain needed
        const unsigned pk = (unsigned)f2h(hn[0]) | ((unsigned)f2h(hn[1]) << 16);
        store_tagged(hb + ((size_t)par * Bb * 256 + (size_t)(r0 + erow) * 256
                           + ct * 16 + (ecp >> 1)) * 2, pk, (unsigned)(p + 1));

        // fp32 output store — off the critical chain
        float2 ho; ho.x = hn[0]; ho.y = hn[1];
        *(float2*)(out_hid + ((size_t)(r0 + erow) * Tt + p) * Hh + ct * CT + ecp) = ho;
        // no end-of-loop sync: next step uses opposite-parity red/ev buffers
    }
}

// out_int = softplus(out_hid @ Wi + bi) as MFMA GEMM. 1024 blocks x 128 rows.
__global__ __launch_bounds__(NTHR)
void nhp_intens(const float* __restrict__ out_hid, const float* __restrict__ Wi,
                const float* __restrict__ bi, float* __restrict__ out_int) {
    const int tid  = threadIdx.x;
    const int w    = tid >> 6;
    const int lane = tid & 63;
    const int col  = lane & 15, kgrp = lane >> 4;

    // Wi fp16 B-frags: 2 e-tiles x 16 k-chunks, register-resident
    f16x8 Bfi[2][16];
    #pragma unroll
    for (int n = 0; n < 2; ++n)
        #pragma unroll
        for (int kk = 0; kk < 16; ++kk) {
            const int k0 = kk * 32 + kgrp * 8;
            union { f16x8 v; unsigned u[4]; } tmp;
            #pragma unroll
            for (int r = 0; r < 4; ++r) {
                const float w0 = Wi[(size_t)(k0 + 2 * r)     * Ee + n * 16 + col];
                const float w1 = Wi[(size_t)(k0 + 2 * r + 1) * Ee + n * 16 + col];
                tmp.u[r] = (unsigned)f2h(w0) | ((unsigned)f2h(w1) << 16);
            }
            Bfi[n][kk] = tmp.v;
        }
    const float bv[2] = { bi[col], bi[16 + col] };

    #pragma unroll
    for (int it = 0; it < 2; ++it) {
        const size_t rowbase = (size_t)blockIdx.x * 128 + (w * 2 + it) * 16;
        f32x4 acc0 = (f32x4){0.f,0.f,0.f,0.f}, acc1 = acc0;
        #pragma unroll
        for (int kk = 0; kk < 16; ++kk) {
            const float* hp = out_hid + (rowbase + (lane & 15)) * Hh + kk * 32 + kgrp * 8;
            const float4 hA = *(const float4*)hp;
            const float4 hB = *(const float4*)(hp + 4);
            union { f16x8 v; unsigned u[4]; } t;
            t.u[0] = (unsigned)f2h(hA.x) | ((unsigned)f2h(hA.y) << 16);
            t.u[1] = (unsigned)f2h(hA.z) | ((unsigned)f2h(hA.w) << 16);
            t.u[2] = (unsigned)f2h(hB.x) | ((unsigned)f2h(hB.y) << 16);
            t.u[3] = (unsigned)f2h(hB.z) | ((unsigned)f2h(hB.w) << 16);
            acc0 = __builtin_amdgcn_mfma_f32_16x16x32_f16(t.v, Bfi[0][kk], acc0, 0, 0, 0);
            acc1 = __builtin_amdgcn_mfma_f32_16x16x32_f16(t.v, Bfi[1][kk], acc1, 0, 0, 0);
        }
        #pragma unroll
        for (int i = 0; i < 4; ++i) {
            const size_t row = rowbase + kgrp * 4 + i;
            out_int[row * Ee + col]      = softplusf(acc0[i] + bv[0]);
            out_int[row * Ee + 16 + col] = softplusf(acc1[i] + bv[1]);
        }
    }
}

extern "C" void kernel_launch(void* const* d_in, const int* in_sizes, int n_in,
                              void* d_out, int out_size, void* d_ws, size_t ws_size,
                              hipStream_t stream) {
    const int*   events = (const int*)d_in[0];
    const float* times  = (const float*)d_in[1];
    const float* emb    = (const float*)d_in[2];
    const float* Wg     = (const float*)d_in[3];
    const float* bg     = (const float*)d_in[4];
    const float* Wi     = (const float*)d_in[5];
    const float* bi     = (const float*)d_in[6];
    float* out_int = (float*)d_out;
    float* out_hid = out_int + (size_t)Bb * Tt * Ee;
    unsigned* hb = (unsigned*)d_ws;  // 2 bufs x 256 rows x 256 units x 8B = 1MB

    hipMemsetAsync(hb, 0, 2u * Bb * 256 * 8, stream);   // clear tags (replay-safe)
    hipLaunchKernelGGL(nhp_scan, dim3(256), dim3(NTHR), 0, stream,
                       events, times, emb, Wg, bg, out_hid, hb);
    hipLaunchKernelGGL(nhp_intens, dim3((Bb * Tt) / 128), dim3(NTHR), 0, stream,
                       out_hid, Wi, bi, out_int);
}